// Round 5
// baseline (1937.955 us; speedup 1.0000x reference)
//
#include <hip/hip_runtime.h>
#include <hip/hip_bf16.h>
#include <stdint.h>

// GCNDecoder, 1-buffer, 6 coalesced GEMM passes (BM=64, BN=256, K=256):
//  P1: gather->G4 -> stats4              P3: gather->G4 -> h=act4 -> buf
//  P4: h->G1 -> stats1                   P6: h->G1 -> out1=act1+h(aT) -> buf (in place)
//  P7: out1->G2 -> stats2                P9: out1->G2 -> out[e]=bf+(act2+out1).wf  (direct)
// All global accesses lane-contiguous (16B/lane); Wt reordered [ks][n][64]; B reg-prefetch;
// stores staged through LDS; stats atomics 8-way sliced with block-level LDS pre-reduce.

typedef __attribute__((ext_vector_type(8))) short short8;
typedef __attribute__((ext_vector_type(4))) float f32x4;

__device__ __forceinline__ unsigned short bf16b(float f) {
  unsigned int u = __float_as_uint(f);
  return (unsigned short)((u + 0x7fffu + ((u >> 16) & 1u)) >> 16);  // RNE
}
__device__ __forceinline__ unsigned int packbf(float lo, float hi) {
  return (unsigned int)bf16b(lo) | ((unsigned int)bf16b(hi) << 16);
}
__device__ __forceinline__ float bfs(short s) { return __uint_as_float(((unsigned int)(unsigned short)s) << 16); }
__device__ __forceinline__ float relu_(float x) { return fmaxf(x, 0.0f); }

// ---- init: zero sliced stats (3 layers x 8 slices x 512) + detect edge_index dtype ----
__global__ __launch_bounds__(256) void k_init(const int* __restrict__ ei,
                                              float* __restrict__ stats, int* __restrict__ flag) {
  const int t = threadIdx.x;
  for (int i = t; i < 12288; i += 256) stats[i] = 0.f;
  if (t == 0) {
    int o = 0;
#pragma unroll
    for (int i = 0; i < 32; ++i) o |= ei[2 * i + 1];
    *flag = (o == 0) ? 1 : 0;  // 1 => int64 pairs, 0 => int32
  }
}

__global__ __launch_bounds__(256) void k_bail(float* __restrict__ out, const float* __restrict__ bfp, int E) {
  const int i = blockIdx.x * 256 + threadIdx.x;
  if (i < E) out[i] = bfp[0];
}

// ---- prep: Wt[ks][n][kk] = bf16(W[ks*64+kk][n]) — per-K-slice contiguous 32KB panels ----
__global__ __launch_bounds__(256) void k_prep(
    const float* __restrict__ W4, const float* __restrict__ W1, const float* __restrict__ W2,
    unsigned short* __restrict__ wt4, unsigned short* __restrict__ wt1, unsigned short* __restrict__ wt2)
{
  const int b = blockIdx.x;           // 0..191
  const int t = threadIdx.x;
  const int wi = b >> 6;
  const int r = b & 63;
  const float* W = (wi == 0) ? W4 : (wi == 1) ? W1 : W2;
  unsigned short* Wt = (wi == 0) ? wt4 : (wi == 1) ? wt1 : wt2;
  const int f = r * 1024 + t * 4;     // flat short index in Wt
  const int ks = f >> 14;
  const int n = (f >> 6) & 255;
  const int kk = f & 63;
  const int k = ks * 64 + kk;
  ushort4 o;
  o.x = bf16b(W[(k + 0) * 256 + n]);
  o.y = bf16b(W[(k + 1) * 256 + n]);
  o.z = bf16b(W[(k + 2) * 256 + n]);
  o.w = bf16b(W[(k + 3) * 256 + n]);
  *(ushort4*)(Wt + f) = o;
}

// ---- stats finalize (8-slice sum): a = g*rsqrt(var+eps); c_std = be - mean*a; c_b = a*bias+c_std
__global__ __launch_bounds__(256) void k_stats(
    const float* __restrict__ stats, const float* __restrict__ g, const float* __restrict__ be,
    const float* __restrict__ bias, float* __restrict__ scale, float invE)
{
  const int c = threadIdx.x;
  float s = 0.f, q = 0.f;
#pragma unroll
  for (int sl = 0; sl < 8; ++sl) { s += stats[sl * 512 + c]; q += stats[sl * 512 + 256 + c]; }
  const float mean = s * invE;
  const float var = q * invE - mean * mean;
  const float a = g[c] * rsqrtf(var + 1e-5f);
  const float cstd = be[c] - mean * a;
  scale[c] = a;
  scale[256 + c] = cstd;
  scale[512 + c] = fmaf(a, bias[c], cstd);
}

// ---- main pass: 64x256 tile, K=256 (4 slices of 64), 8 waves (2 row x 4 col) ----
// APROC: 0 = gather x (fp32->bf16) via edge_index; 1 = bf16 rows from Av (padded buf)
// EPI:   0 = column stats (bias added)       1 = act -> store bf16 tile
//        2 = act + resid(aT) -> store        3 = (act + aT).wf -> out[e] direct
template<int APROC, int EPI>
__global__ __launch_bounds__(512) void k_g(
    const void* Av, const int* __restrict__ ei, const int* __restrict__ flagp,
    const unsigned short* __restrict__ Wt, const float* __restrict__ bias,
    const float* __restrict__ sc, const float* __restrict__ wf,
    unsigned short* __restrict__ Yout, float* __restrict__ stats,
    float* __restrict__ out, const float* __restrict__ bfp, int E)
{
  __shared__ __align__(16) char aT[32768];   // 64 rows x 512B, 16B chunks XOR-swizzled by (row&7)<<4
  __shared__ __align__(16) char bT[32768];   // 256 n-rows x 128B, XOR-swizzled by (n&7)<<4
  __shared__ float sS[768];                  // a, c_b, wf
  __shared__ float sRed[1024];               // stats block-reduce / row-dot reduce
  __shared__ int2 eIdx[64];

  const int t = threadIdx.x;
  const int m0 = blockIdx.x * 64;

  if (EPI >= 1 && t < 256) {
    sS[t] = sc[t];
    sS[256 + t] = sc[512 + t];               // bias-folded c
    if (EPI == 3) sS[512 + t] = wf[t];
  }
  if (APROC == 0 && t < 64) {
    int e = m0 + t; if (e >= E) e = E - 1;
    int2 v;
    if (flagp[0]) { v.x = ei[2 * e]; v.y = ei[2 * (E + e)]; }
    else          { v.x = ei[e];     v.y = ei[E + e]; }
    eIdx[t] = v;
  }

  // ---- B prefetch (ks=0): lane-contiguous 16B chunks of the 32KB panel ----
  uint4 br[4];
#pragma unroll
  for (int r = 0; r < 4; ++r)
    br[r] = *(const uint4*)(Wt + (t + r * 512) * 8);

  // ---- A stage: linear 32KB tile copy (or gather-convert), lane-contiguous ----
  if (APROC == 1) {
    const char* src = (const char*)Av + (size_t)m0 * 512;
#pragma unroll
    for (int r = 0; r < 4; ++r) {
      const int c = t + r * 512;
      uint4 v = *(const uint4*)(src + c * 16);
      const int row = c >> 5;
      *(uint4*)(aT + row * 512 + (((c & 31) * 16) ^ ((row & 7) << 4))) = v;
    }
  } else {
    __syncthreads();                         // eIdx visible
    const float* x = (const float*)Av;
#pragma unroll
    for (int r = 0; r < 4; ++r) {
      const int c = t + r * 512;
      const int row = c >> 5;
      const int half = (c >> 4) & 1;
      const int sub = c & 15;
      const int node = half ? eIdx[row].y : eIdx[row].x;
      const float* s = x + node * 128 + sub * 8;
      float4 f0 = *(const float4*)s;
      float4 f1 = *(const float4*)(s + 4);
      uint4 v;
      v.x = packbf(f0.x, f0.y); v.y = packbf(f0.z, f0.w);
      v.z = packbf(f1.x, f1.y); v.w = packbf(f1.z, f1.w);
      *(uint4*)(aT + row * 512 + (((c & 31) * 16) ^ ((row & 7) << 4))) = v;
    }
  }

  const int l = t & 63, wv = t >> 6;
  const int wr = wv >> 2, wc = wv & 3;       // 2 x 4 wave grid
  const int sw = (l & 7) << 4;

  f32x4 acc[2][4];
  f32x4 zz = {0.f, 0.f, 0.f, 0.f};
#pragma unroll
  for (int i = 0; i < 2; ++i)
#pragma unroll
    for (int j = 0; j < 4; ++j) acc[i][j] = zz;

  for (int ks = 0; ks < 4; ++ks) {
#pragma unroll
    for (int r = 0; r < 4; ++r) {            // regs -> bT
      const int c = t + r * 512;
      const int n = c >> 3;
      *(uint4*)(bT + n * 128 + (((c & 7) * 16) ^ ((n & 7) << 4))) = br[r];
    }
    __syncthreads();
    if (ks < 3) {                            // prefetch next panel before MFMAs
      const unsigned short* wn = Wt + (ks + 1) * 16384;
#pragma unroll
      for (int r = 0; r < 4; ++r)
        br[r] = *(const uint4*)(wn + (t + r * 512) * 8);
    }
    const int ar = wr * 32 + (l & 15);
    const int bn = wc * 64 + (l & 15);
#pragma unroll
    for (int kk = 0; kk < 2; ++kk) {
      const int ko = kk * 64 + ((l >> 4) << 4);
      short8 af[2], bfr[4];
      af[0] = *(const short8*)(aT + ar * 512 + ((ks * 128 + ko) ^ sw));
      af[1] = *(const short8*)(aT + (ar + 16) * 512 + ((ks * 128 + ko) ^ sw));
#pragma unroll
      for (int j = 0; j < 4; ++j)
        bfr[j] = *(const short8*)(bT + (bn + j * 16) * 128 + (ko ^ sw));
#pragma unroll
      for (int i = 0; i < 2; ++i)
#pragma unroll
        for (int j = 0; j < 4; ++j)
          acc[i][j] = __builtin_amdgcn_mfma_f32_16x16x32_bf16(af[i], bfr[j], acc[i][j], 0, 0, 0);
    }
    __syncthreads();
  }

  const int colb = wc * 64 + (l & 15);
  const int lr0 = wr * 32 + ((l >> 4) << 2);

  if (EPI == 0) {
    float bj[4];
#pragma unroll
    for (int j = 0; j < 4; ++j) bj[j] = bias[colb + j * 16];
    float ssum[4] = {0.f, 0.f, 0.f, 0.f};
    float ssq[4] = {0.f, 0.f, 0.f, 0.f};
#pragma unroll
    for (int i = 0; i < 2; ++i) {
      const int r0 = m0 + lr0 + i * 16;
#pragma unroll
      for (int j = 0; j < 4; ++j) {
#pragma unroll
        for (int q = 0; q < 4; ++q) {
          float v = acc[i][j][q] + bj[j];
          if (r0 + q < E) { ssum[j] += v; ssq[j] = fmaf(v, v, ssq[j]); }
        }
      }
    }
#pragma unroll
    for (int j = 0; j < 4; ++j) {
      ssum[j] += __shfl_xor(ssum[j], 16); ssum[j] += __shfl_xor(ssum[j], 32);
      ssq[j]  += __shfl_xor(ssq[j], 16);  ssq[j]  += __shfl_xor(ssq[j], 32);
    }
    const int g = l >> 4;
    float sg = (g == 0) ? ssum[0] : (g == 1) ? ssum[1] : (g == 2) ? ssum[2] : ssum[3];
    float qg = (g == 0) ? ssq[0] : (g == 1) ? ssq[1] : (g == 2) ? ssq[2] : ssq[3];
    const int col = wc * 64 + g * 16 + (l & 15);
    sRed[wr * 512 + col] = sg;               // [wr][kind][256]
    sRed[wr * 512 + 256 + col] = qg;
    __syncthreads();
    if (t < 512) {
      float v = sRed[t] + sRed[512 + t];
      atomicAdd(&stats[(blockIdx.x & 7) * 512 + t], v);
    }
    return;
  }

  if (EPI == 3) {                            // final: out[e] = bf + (act2 + out1(aT)).wf
    float dq[2][4];
#pragma unroll
    for (int i = 0; i < 2; ++i)
#pragma unroll
      for (int q = 0; q < 4; ++q) dq[i][q] = 0.f;
#pragma unroll
    for (int j = 0; j < 4; ++j) {
      const int col = colb + j * 16;
      const float a = sS[col], cb = sS[256 + col], w = sS[512 + col];
#pragma unroll
      for (int i = 0; i < 2; ++i) {
#pragma unroll
        for (int q = 0; q < 4; ++q) {
          const int lrow = lr0 + i * 16 + q;
          float v = relu_(fmaf(acc[i][j][q], a, cb)) +
                    bfs(*(const short*)(aT + lrow * 512 + ((col * 2) ^ ((lrow & 7) << 4))));
          dq[i][q] = fmaf(v, w, dq[i][q]);
        }
      }
    }
#pragma unroll
    for (int i = 0; i < 2; ++i)
#pragma unroll
      for (int q = 0; q < 4; ++q) {
        float p = dq[i][q];
        p += __shfl_xor(p, 1); p += __shfl_xor(p, 2); p += __shfl_xor(p, 4); p += __shfl_xor(p, 8);
        if ((l & 15) == 0) sRed[(lr0 + i * 16 + q) * 4 + wc] = p;
      }
    __syncthreads();
    if (t < 64) {
      const int e = m0 + t;
      if (e < E) out[e] = sRed[t * 4] + sRed[t * 4 + 1] + sRed[t * 4 + 2] + sRed[t * 4 + 3] + bfp[0];
    }
    return;
  }

  // EPI 1/2: act (+resid from aT) -> pack to bT -> linear coalesced copy-out
  const int odd = l & 1;
#pragma unroll
  for (int i = 0; i < 2; ++i) {
    const int r0 = lr0 + i * 16;
#pragma unroll
    for (int j = 0; j < 4; ++j) {
      const int col = colb + j * 16;
      const float a = sS[col], cb = sS[256 + col];
      float v0 = relu_(fmaf(acc[i][j][0], a, cb));
      float v1 = relu_(fmaf(acc[i][j][1], a, cb));
      float v2 = relu_(fmaf(acc[i][j][2], a, cb));
      float v3 = relu_(fmaf(acc[i][j][3], a, cb));
      if (EPI == 2) {
        v0 += bfs(*(const short*)(aT + (r0 + 0) * 512 + ((col * 2) ^ (((r0 + 0) & 7) << 4))));
        v1 += bfs(*(const short*)(aT + (r0 + 1) * 512 + ((col * 2) ^ (((r0 + 1) & 7) << 4))));
        v2 += bfs(*(const short*)(aT + (r0 + 2) * 512 + ((col * 2) ^ (((r0 + 2) & 7) << 4))));
        v3 += bfs(*(const short*)(aT + (r0 + 3) * 512 + ((col * 2) ^ (((r0 + 3) & 7) << 4))));
      }
      float p0 = __shfl_xor(v0, 1), p1 = __shfl_xor(v1, 1);
      float p2 = __shfl_xor(v2, 1), p3 = __shfl_xor(v3, 1);
      float loA = odd ? p2 : v0, hiA = odd ? v2 : p0;
      float loB = odd ? p3 : v1, hiB = odd ? v3 : p1;
      const int ra = r0 + (odd ? 2 : 0);
      const int cp2 = (col & ~1) * 2;
      *(unsigned int*)(bT + (ra + 0) * 512 + (cp2 ^ (((ra + 0) & 7) << 4))) = packbf(loA, hiA);
      *(unsigned int*)(bT + (ra + 1) * 512 + (cp2 ^ (((ra + 1) & 7) << 4))) = packbf(loB, hiB);
    }
  }
  __syncthreads();
  {
    char* dst = (char*)Yout + (size_t)m0 * 512;
#pragma unroll
    for (int r = 0; r < 4; ++r) {
      const int c = t + r * 512;
      const int row = c >> 5;
      uint4 v = *(const uint4*)(bT + row * 512 + (((c & 31) * 16) ^ ((row & 7) << 4)));
      *(uint4*)(dst + c * 16) = v;
    }
  }
}

extern "C" void kernel_launch(void* const* d_in, const int* in_sizes, int n_in,
                              void* d_out, int out_size, void* d_ws, size_t ws_size,
                              hipStream_t stream) {
  const float* x   = (const float*)d_in[0];
  const int*   ei  = (const int*)d_in[1];   // int32 or int64-pairs (runtime-detected)
  const float* W4  = (const float*)d_in[2];
  const float* b4  = (const float*)d_in[3];
  const float* g4  = (const float*)d_in[4];
  const float* be4 = (const float*)d_in[5];
  const float* W1  = (const float*)d_in[6];
  const float* b1  = (const float*)d_in[7];
  const float* g1  = (const float*)d_in[8];
  const float* be1 = (const float*)d_in[9];
  const float* W2  = (const float*)d_in[10];
  const float* b2  = (const float*)d_in[11];
  const float* g2  = (const float*)d_in[12];
  const float* be2 = (const float*)d_in[13];
  const float* Wf  = (const float*)d_in[14];
  const float* bfp = (const float*)d_in[15];
  float* out = (float*)d_out;

  const int E = out_size;                   // output length IS the edge count
  const int MT = (E + 63) / 64;             // 7813
  const float invE = 1.0f / (float)E;

  char* ws = (char*)d_ws;
  unsigned short* wt4 = (unsigned short*)(ws);
  unsigned short* wt1 = (unsigned short*)(ws + 131072);
  unsigned short* wt2 = (unsigned short*)(ws + 262144);
  float* stats = (float*)(ws + 393216);     // 3 layers x 8 slices x 512 = 49152 B
  float* scale = (float*)(ws + 442368);     // 3 x (a, c_std, c_b)[256] = 9216 B
  int*   flag  = (int*)(ws + 451584);
  const size_t fixed = 458752;
  const size_t bufbytes = (size_t)MT * 32768;
  unsigned short* buf = (unsigned short*)(ws + fixed);

  if (ws_size < fixed + bufbytes) {         // should not happen (round-3 evidence)
    k_bail<<<(E + 255) / 256, 256, 0, stream>>>(out, bfp, E);
    return;
  }

  k_init<<<1, 256, 0, stream>>>(ei, stats, flag);
  k_prep<<<192, 256, 0, stream>>>(W4, W1, W2, wt4, wt1, wt2);

  // P1: gather -> G4 -> stats4
  k_g<0, 0><<<MT, 512, 0, stream>>>((const void*)x, ei, flag, wt4, b4,
                                    nullptr, nullptr, nullptr, stats, nullptr, bfp, E);
  k_stats<<<1, 256, 0, stream>>>(stats, g4, be4, b4, scale, invE);
  // P3: gather -> G4 -> h = act4 -> buf
  k_g<0, 1><<<MT, 512, 0, stream>>>((const void*)x, ei, flag, wt4, nullptr,
                                    scale, nullptr, buf, nullptr, nullptr, bfp, E);
  // P4: h -> G1 -> stats1
  k_g<1, 0><<<MT, 512, 0, stream>>>((const void*)buf, nullptr, flag, wt1, b1,
                                    nullptr, nullptr, nullptr, stats + 4096, nullptr, bfp, E);
  k_stats<<<1, 256, 0, stream>>>(stats + 4096, g1, be1, b1, scale + 768, invE);
  // P6: h -> G1 -> out1 = act1 + h(aT) -> buf (in place)
  k_g<1, 2><<<MT, 512, 0, stream>>>((const void*)buf, nullptr, flag, wt1, nullptr,
                                    scale + 768, nullptr, buf, nullptr, nullptr, bfp, E);
  // P7: out1 -> G2 -> stats2
  k_g<1, 0><<<MT, 512, 0, stream>>>((const void*)buf, nullptr, flag, wt2, b2,
                                    nullptr, nullptr, nullptr, stats + 8192, nullptr, bfp, E);
  k_stats<<<1, 256, 0, stream>>>(stats + 8192, g2, be2, b2, scale + 1536, invE);
  // P9: out1 -> G2 -> out[e] = bf + (act2 + out1(aT)) . wf
  k_g<1, 3><<<MT, 512, 0, stream>>>((const void*)buf, nullptr, flag, wt2, nullptr,
                                    scale + 1536, Wf, nullptr, nullptr, out, bfp, E);
}

// Round 6
// 610.236 us; speedup vs baseline: 3.1757x; 3.1757x over previous
//
#include <hip/hip_runtime.h>
#include <hip/hip_bf16.h>
#include <stdint.h>

// GCNDecoder: persistent-block GEMM passes, B fully LDS-resident (128KB) + A tile (32KB) = 160KB.
// Grid 256 (1 block/CU), each block owns ~31 contiguous 64-row tiles; B staged once per pass.
// Schedule (one 256MB buf, in-place):
//  K1: gather->G4 -> buf=Y4raw, stats4      K2: Y4raw --act4--> h -> G1 -> stats1; buf=h
//  K3: h -> G1 -> out1=act1+h -> buf=out1; out += out1.wf   K4: out1 -> G2 -> stats2; buf=Y2raw
//  K5: out += act2(Y2raw).wf  (light scan)
// Stats/scales in registers (cols are thread-invariant); stats -> global atomics once per block.

typedef __attribute__((ext_vector_type(8))) short short8;
typedef __attribute__((ext_vector_type(4))) float f32x4;

__device__ __forceinline__ unsigned short bf16b(float f) {
  unsigned int u = __float_as_uint(f);
  return (unsigned short)((u + 0x7fffu + ((u >> 16) & 1u)) >> 16);  // RNE
}
__device__ __forceinline__ unsigned int packbf(float lo, float hi) {
  return (unsigned int)bf16b(lo) | ((unsigned int)bf16b(hi) << 16);
}
__device__ __forceinline__ float bflo(unsigned int u) { return __uint_as_float(u << 16); }
__device__ __forceinline__ float bfhi(unsigned int u) { return __uint_as_float(u & 0xffff0000u); }
__device__ __forceinline__ float bfs(short s) { return __uint_as_float(((unsigned int)(unsigned short)s) << 16); }
__device__ __forceinline__ float relu_(float x) { return fmaxf(x, 0.0f); }

// ---- tiny kernels ----
__global__ __launch_bounds__(256) void k_init(const int* __restrict__ ei,
                                              float* __restrict__ stats, int* __restrict__ flag) {
  const int t = threadIdx.x;
  for (int i = t; i < 1536; i += 256) stats[i] = 0.f;
  if (t == 0) {
    int o = 0;
#pragma unroll
    for (int i = 0; i < 32; ++i) o |= ei[2 * i + 1];
    *flag = (o == 0) ? 1 : 0;  // 1 => int64 pairs, 0 => int32
  }
}

__global__ __launch_bounds__(256) void k_seed(float* __restrict__ out, const float* __restrict__ bfp, int E) {
  const int i = blockIdx.x * 256 + threadIdx.x;
  if (i < E) out[i] = bfp[0];
}

// Wt[n][k] = bf16(W[k][n])  (n-major, 512B rows)
__global__ __launch_bounds__(256) void k_prep(
    const float* __restrict__ W4, const float* __restrict__ W1, const float* __restrict__ W2,
    unsigned short* __restrict__ wt4, unsigned short* __restrict__ wt1, unsigned short* __restrict__ wt2)
{
  const int b = blockIdx.x;
  const int t = threadIdx.x;
  const int wi = b >> 6;
  const int r = b & 63;
  const float* W = (wi == 0) ? W4 : (wi == 1) ? W1 : W2;
  unsigned short* Wt = (wi == 0) ? wt4 : (wi == 1) ? wt1 : wt2;
  const int flat = r * 1024 + t * 4;
  const int n = flat >> 8;
  const int k = flat & 255;
  ushort4 o;
  o.x = bf16b(W[(k + 0) * 256 + n]);
  o.y = bf16b(W[(k + 1) * 256 + n]);
  o.z = bf16b(W[(k + 2) * 256 + n]);
  o.w = bf16b(W[(k + 3) * 256 + n]);
  *(ushort4*)(Wt + flat) = o;
}

// stats -> scale[c]=a, scale[256+c]=c_std, scale[512+c]=c_b (bias folded)
__global__ __launch_bounds__(256) void k_stats(
    const float* __restrict__ stats, const float* __restrict__ g, const float* __restrict__ be,
    const float* __restrict__ bias, float* __restrict__ scale, float invE)
{
  const int c = threadIdx.x;
  const float mean = stats[c] * invE;
  const float var = stats[256 + c] * invE - mean * mean;
  const float a = g[c] * rsqrtf(var + 1e-5f);
  const float cstd = be[c] - mean * a;
  scale[c] = a;
  scale[256 + c] = cstd;
  scale[512 + c] = fmaf(a, bias[c], cstd);
}

// ---- persistent GEMM pass ----
// MODE 1: A=gather(x); store raw acc; stats      MODE 2: A=act4(buf); store staged A (=h); stats
// MODE 3: A=buf; out1=act+resid(A); store out1; out += out1.wf      MODE 4: A=buf; store raw; stats
template<int MODE>
__global__ __launch_bounds__(512, 1) void kp(
    const void* Asrc, const int* __restrict__ ei, const int* __restrict__ flagp,
    const unsigned short* __restrict__ Wt, const float* __restrict__ bias,
    const float* __restrict__ scst, const float* __restrict__ scep, const float* __restrict__ wf,
    unsigned short* __restrict__ buf, float* __restrict__ stats, float* __restrict__ out,
    int E, int MT)
{
  __shared__ __align__(16) char bB[131072];  // 256 n-rows x 512B (full K), XOR-swz by (n&7)<<4
  __shared__ __align__(16) char aT[32768];   // 64 rows x 512B, XOR-swz by (row&7)<<4

  const int t = threadIdx.x;
  const int b = blockIdx.x;
  const int per = MT >> 8, rem = MT & 255;
  const int t0 = b * per + (b < rem ? b : rem);
  const int t1 = t0 + per + (b < rem ? 1 : 0);

  const int l = t & 63, wv = t >> 6;
  const int wr = wv >> 2, wc = wv & 3;       // 2 x 4 wave grid
  const int sw = (l & 7) << 4;
  const int subc = t & 31, rB = t >> 5;      // staging: rows rB+r*16, byte-cols subc*16
  const int colb = wc * 64 + (l & 15);
  const int lr0 = wr * 32 + ((l >> 4) << 2);
  const int flag = (MODE == 1) ? flagp[0] : 0;

  float bj[4];                               // stats bias (MODE 1,2,4)
  if (MODE != 3) {
#pragma unroll
    for (int j = 0; j < 4; ++j) bj[j] = bias[colb + j * 16];
  }
  float aS[8], cS[8];                        // staging act scale (MODE 2), cols subc*8..+8
  if (MODE == 2) {
#pragma unroll
    for (int k = 0; k < 8; ++k) { aS[k] = scst[subc * 8 + k]; cS[k] = scst[512 + subc * 8 + k]; }
  }
  float aE[4], cE[4], wE[4];                 // epilogue act scale + wf (MODE 3)
  if (MODE == 3) {
#pragma unroll
    for (int j = 0; j < 4; ++j) {
      const int c = colb + j * 16;
      aE[j] = scep[c]; cE[j] = scep[512 + c]; wE[j] = wf[c];
    }
  }
  float ssum[4] = {0.f, 0.f, 0.f, 0.f}, ssq[4] = {0.f, 0.f, 0.f, 0.f};

  // ---- prefetch A(t0) ----
  uint4 pf[4];
#define PREFETCH(TT)                                                              \
  if (MODE == 1) {                                                                \
    const float* xf = (const float*)Asrc;                                         \
    _Pragma("unroll")                                                             \
    for (int r = 0; r < 4; ++r) {                                                 \
      const int row = rB + r * 16;                                                \
      int e = (TT) * 64 + row; if (e >= E) e = E - 1;                             \
      const int idx = (subc < 16) ? e : (E + e);                                  \
      const int node = flag ? ei[2 * idx] : ei[idx];                              \
      const float* s = xf + node * 128 + (subc & 15) * 8;                         \
      float4 f0 = *(const float4*)s;                                              \
      float4 f1 = *(const float4*)(s + 4);                                        \
      pf[r].x = packbf(f0.x, f0.y); pf[r].y = packbf(f0.z, f0.w);                 \
      pf[r].z = packbf(f1.x, f1.y); pf[r].w = packbf(f1.z, f1.w);                 \
    }                                                                             \
  } else {                                                                        \
    const uint4* s = (const uint4*)((const char*)Asrc + (size_t)(TT) * 32768);    \
    _Pragma("unroll")                                                             \
    for (int r = 0; r < 4; ++r) pf[r] = s[t + r * 512];                           \
  }

#define STAGE_A                                                                   \
  _Pragma("unroll")                                                               \
  for (int r = 0; r < 4; ++r) {                                                   \
    const int row = rB + r * 16;                                                  \
    uint4 v = pf[r];                                                              \
    if (MODE == 2) {                                                              \
      unsigned int* vp = (unsigned int*)&v;                                       \
      _Pragma("unroll")                                                           \
      for (int h2 = 0; h2 < 4; ++h2) {                                            \
        float lo = relu_(fmaf(bflo(vp[h2]), aS[h2 * 2], cS[h2 * 2]));             \
        float hi = relu_(fmaf(bfhi(vp[h2]), aS[h2 * 2 + 1], cS[h2 * 2 + 1]));     \
        vp[h2] = packbf(lo, hi);                                                  \
      }                                                                           \
    }                                                                             \
    *(uint4*)(aT + row * 512 + ((subc * 16) ^ ((row & 7) << 4))) = v;             \
  }

  PREFETCH(t0);
  // ---- stage B once (coalesced; 2-way LDS aliasing only) ----
#pragma unroll
  for (int r = 0; r < 16; ++r) {
    const int c = t + r * 512;
    uint4 v = *(const uint4*)(Wt + c * 8);
    const int n = c >> 5;
    *(uint4*)(bB + n * 512 + (((c & 31) * 16) ^ ((n & 7) << 4))) = v;
  }
  STAGE_A;
  __syncthreads();

  const int ar = wr * 32 + (l & 15);
  const int bn = wc * 64 + (l & 15);

  for (int tt = t0;;) {
    const bool more = (tt + 1 < t1);
    if (more) PREFETCH(tt + 1);

    f32x4 acc[2][4];
    f32x4 zz = {0.f, 0.f, 0.f, 0.f};
#pragma unroll
    for (int i = 0; i < 2; ++i)
#pragma unroll
      for (int j = 0; j < 4; ++j) acc[i][j] = zz;

    // ---- barrier-free K loop: A and B both resident ----
#pragma unroll
    for (int ks = 0; ks < 4; ++ks) {
#pragma unroll
      for (int kk = 0; kk < 2; ++kk) {
        const int kb = ks * 128 + kk * 64 + ((l >> 4) << 4);
        short8 af[2], bfr[4];
        af[0] = *(const short8*)(aT + ar * 512 + (kb ^ sw));
        af[1] = *(const short8*)(aT + (ar + 16) * 512 + (kb ^ sw));
#pragma unroll
        for (int j = 0; j < 4; ++j)
          bfr[j] = *(const short8*)(bB + (bn + j * 16) * 512 + (kb ^ sw));
#pragma unroll
        for (int i = 0; i < 2; ++i)
#pragma unroll
          for (int j = 0; j < 4; ++j)
            acc[i][j] = __builtin_amdgcn_mfma_f32_16x16x32_bf16(af[i], bfr[j], acc[i][j], 0, 0, 0);
      }
    }

    if (MODE != 3) {                         // stats accumulate in registers
#pragma unroll
      for (int i = 0; i < 2; ++i) {
        const int r0 = tt * 64 + lr0 + i * 16;
#pragma unroll
        for (int j = 0; j < 4; ++j) {
#pragma unroll
          for (int q = 0; q < 4; ++q) {
            const float v = acc[i][j][q] + bj[j];
            if (r0 + q < E) { ssum[j] += v; ssq[j] = fmaf(v, v, ssq[j]); }
          }
        }
      }
    } else {                                 // MODE 3: out1 = act1 + resid(aT); dot wf
      float dq[2][4];
#pragma unroll
      for (int i = 0; i < 2; ++i)
#pragma unroll
        for (int q = 0; q < 4; ++q) dq[i][q] = 0.f;
#pragma unroll
      for (int i = 0; i < 2; ++i) {
#pragma unroll
        for (int j = 0; j < 4; ++j) {
#pragma unroll
          for (int q = 0; q < 4; ++q) {
            const int lrow = lr0 + i * 16 + q;
            const float h = bfs(*(const short*)(aT + lrow * 512 +
                                (((colb + j * 16) * 2) ^ ((lrow & 7) << 4))));
            const float v = relu_(fmaf(acc[i][j][q], aE[j], cE[j])) + h;
            acc[i][j][q] = v;                // reuse acc as out1 storage for pack
            dq[i][q] = fmaf(v, wE[j], dq[i][q]);
          }
        }
      }
#pragma unroll
      for (int i = 0; i < 2; ++i)
#pragma unroll
        for (int q = 0; q < 4; ++q) {
          float p = dq[i][q];
          p += __shfl_xor(p, 1); p += __shfl_xor(p, 2); p += __shfl_xor(p, 4); p += __shfl_xor(p, 8);
          if ((l & 15) == 0) {
            const int row = tt * 64 + lr0 + i * 16 + q;
            if (row < E) atomicAdd(&out[row], p);
          }
        }
    }
    __syncthreads();                         // all aT reads done

    if (MODE != 2) {                         // pack acc (raw or out1) -> aT
      const int odd = l & 1;
#pragma unroll
      for (int i = 0; i < 2; ++i) {
        const int r0 = lr0 + i * 16;
#pragma unroll
        for (int j = 0; j < 4; ++j) {
          float v0 = acc[i][j][0], v1 = acc[i][j][1], v2 = acc[i][j][2], v3 = acc[i][j][3];
          float p0 = __shfl_xor(v0, 1), p1 = __shfl_xor(v1, 1);
          float p2 = __shfl_xor(v2, 1), p3 = __shfl_xor(v3, 1);
          float loA = odd ? p2 : v0, hiA = odd ? v2 : p0;
          float loB = odd ? p3 : v1, hiB = odd ? v3 : p1;
          const int ra = r0 + (odd ? 2 : 0);
          const int cp2 = ((colb + j * 16) & ~1) * 2;
          *(unsigned int*)(aT + (ra + 0) * 512 + (cp2 ^ (((ra + 0) & 7) << 4))) = packbf(loA, hiA);
          *(unsigned int*)(aT + (ra + 1) * 512 + (cp2 ^ (((ra + 1) & 7) << 4))) = packbf(loB, hiB);
        }
      }
      __syncthreads();                       // staging complete
    }

    {                                        // coalesced copy-out (MODE2: h; else packed)
      char* d = (char*)buf + (size_t)tt * 32768;
#pragma unroll
      for (int r = 0; r < 4; ++r) {
        const int c = t + r * 512;
        const int row = c >> 5;
        uint4 v = *(const uint4*)(aT + row * 512 + (((c & 31) * 16) ^ ((row & 7) << 4)));
        *(uint4*)(d + c * 16) = v;
      }
    }

    ++tt;
    if (!(tt < t1)) break;
    __syncthreads();                         // copy-out reads done
    STAGE_A;                                 // A(tt) from prefetch regs
    __syncthreads();
  }

  if (MODE != 3) {                           // stats tail: one atomic burst per block
#pragma unroll
    for (int j = 0; j < 4; ++j) {
      ssum[j] += __shfl_xor(ssum[j], 16); ssum[j] += __shfl_xor(ssum[j], 32);
      ssq[j]  += __shfl_xor(ssq[j], 16);  ssq[j]  += __shfl_xor(ssq[j], 32);
    }
    const int g = l >> 4;
    float sg = (g == 0) ? ssum[0] : (g == 1) ? ssum[1] : (g == 2) ? ssum[2] : ssum[3];
    float qg = (g == 0) ? ssq[0] : (g == 1) ? ssq[1] : (g == 2) ? ssq[2] : ssq[3];
    const int col = wc * 64 + g * 16 + (l & 15);
    atomicAdd(&stats[col], sg);
    atomicAdd(&stats[256 + col], qg);
  }
#undef PREFETCH
#undef STAGE_A
}

// ---- final scan: out[e] += relu(a2*Y2+cb2).wf  (8 thr/row, 64B/thread contiguous) ----
__global__ __launch_bounds__(512) void k_fin(
    const unsigned short* __restrict__ Y, const float* __restrict__ scale,
    const float* __restrict__ wf, float* __restrict__ out, int E)
{
  __shared__ float sS[768];
  const int t = threadIdx.x;
  if (t < 256) { sS[t] = scale[t]; sS[256 + t] = scale[512 + t]; sS[512 + t] = wf[t]; }
  __syncthreads();
  const int row = blockIdx.x * 64 + (t >> 3);
  const int p = t & 7;
  const unsigned short* r = Y + (size_t)row * 256 + p * 32;
  float acc = 0.f;
#pragma unroll
  for (int m = 0; m < 4; ++m) {
    uint4 v = *(const uint4*)(r + m * 8);
    const int k0 = p * 32 + m * 8;
    const unsigned int* vp = (const unsigned int*)&v;
#pragma unroll
    for (int h = 0; h < 4; ++h) {
      const int k = k0 + h * 2;
      acc = fmaf(relu_(fmaf(bflo(vp[h]), sS[k], sS[256 + k])), sS[512 + k], acc);
      acc = fmaf(relu_(fmaf(bfhi(vp[h]), sS[k + 1], sS[256 + k + 1])), sS[512 + k + 1], acc);
    }
  }
  acc += __shfl_xor(acc, 1); acc += __shfl_xor(acc, 2); acc += __shfl_xor(acc, 4);
  if (p == 0 && row < E) out[row] += acc;
}

__global__ __launch_bounds__(256) void k_bail(float* __restrict__ out, const float* __restrict__ bfp, int E) {
  const int i = blockIdx.x * 256 + threadIdx.x;
  if (i < E) out[i] = bfp[0];
}

extern "C" void kernel_launch(void* const* d_in, const int* in_sizes, int n_in,
                              void* d_out, int out_size, void* d_ws, size_t ws_size,
                              hipStream_t stream) {
  const float* x   = (const float*)d_in[0];
  const int*   ei  = (const int*)d_in[1];
  const float* W4  = (const float*)d_in[2];
  const float* b4  = (const float*)d_in[3];
  const float* g4  = (const float*)d_in[4];
  const float* be4 = (const float*)d_in[5];
  const float* W1  = (const float*)d_in[6];
  const float* b1  = (const float*)d_in[7];
  const float* g1  = (const float*)d_in[8];
  const float* be1 = (const float*)d_in[9];
  const float* W2  = (const float*)d_in[10];
  const float* b2  = (const float*)d_in[11];
  const float* g2  = (const float*)d_in[12];
  const float* be2 = (const float*)d_in[13];
  const float* Wf  = (const float*)d_in[14];
  const float* bfp = (const float*)d_in[15];
  float* out = (float*)d_out;

  const int E = out_size;
  const int MT = (E + 63) / 64;
  const float invE = 1.0f / (float)E;

  char* ws = (char*)d_ws;
  unsigned short* wt4 = (unsigned short*)(ws);
  unsigned short* wt1 = (unsigned short*)(ws + 131072);
  unsigned short* wt2 = (unsigned short*)(ws + 262144);
  float* stats = (float*)(ws + 393216);     // 3 x 512
  float* scale = (float*)(ws + 399360);     // 3 x (a, c_std, c_b)[256]
  int*   flag  = (int*)(ws + 408576);
  const size_t fixed = 409600;
  const size_t bufbytes = (size_t)MT * 32768;
  unsigned short* buf = (unsigned short*)(ws + fixed);

  if (ws_size < fixed + bufbytes) {
    k_bail<<<(E + 255) / 256, 256, 0, stream>>>(out, bfp, E);
    return;
  }

  k_init<<<1, 256, 0, stream>>>(ei, stats, flag);
  k_prep<<<192, 256, 0, stream>>>(W4, W1, W2, wt4, wt1, wt2);

  // K1: gather -> G4 -> buf = Y4raw, stats4
  kp<1><<<256, 512, 0, stream>>>((const void*)x, ei, flag, wt4, b4,
                                 nullptr, nullptr, nullptr, buf, stats, nullptr, E, MT);
  k_stats<<<1, 256, 0, stream>>>(stats, g4, be4, b4, scale, invE);
  // K2: Y4raw --act4--> h -> G1 -> stats1; buf = h
  kp<2><<<256, 512, 0, stream>>>((const void*)buf, nullptr, flag, wt1, b1,
                                 scale, nullptr, nullptr, buf, stats + 512, nullptr, E, MT);
  k_stats<<<1, 256, 0, stream>>>(stats + 512, g1, be1, b1, scale + 768, invE);
  k_seed<<<(E + 255) / 256, 256, 0, stream>>>(out, bfp, E);
  // K3: h -> G1 -> out1 = act1 + h; buf = out1; out += out1.wf
  kp<3><<<256, 512, 0, stream>>>((const void*)buf, nullptr, flag, wt1, nullptr,
                                 nullptr, scale + 768, Wf, buf, nullptr, out, E, MT);
  // K4: out1 -> G2 -> stats2; buf = Y2raw
  kp<4><<<256, 512, 0, stream>>>((const void*)buf, nullptr, flag, wt2, b2,
                                 nullptr, nullptr, nullptr, buf, stats + 1024, nullptr, E, MT);
  k_stats<<<1, 256, 0, stream>>>(stats + 1024, g2, be2, b2, scale + 1536, invE);
  // K5: out += act2(Y2raw).wf
  k_fin<<<MT, 512, 0, stream>>>(buf, scale + 1536, Wf, out, E);
}